// Round 5
// baseline (549.249 us; speedup 1.0000x reference)
//
#include <hip/hip_runtime.h>
#include <hip/hip_fp16.h>
#include <hip/hip_cooperative_groups.h>

namespace cg = cooperative_groups;

// GCN: 100K nodes, 1.6M edges, 128 -> 128 -> 128 -> 64 (fp32 in/out)
// v6 = v3 hot path (best: 455.8us) + all preprocessing fused into ONE
// cooperative kernel (memset+wt_conv+bucket_count+scan+p1+p2 -> prep_all,
// grid.sync() between phases). Theory: ~170us of the total is launch
// gaps across 10 dispatches; this cuts 10 -> 5. Hot kernels unchanged.
// v5 (wave-independent fused MFMA) reverted: 4x MFMA + 4x B-loads +
// occupancy 77->49% regressed 91->141us.

#define NN 100000
#define NE 1600000
#define TT (NE + NN)              // edges + self loops
#define BSH 9                      // bucket = dst >> 9 (512 nodes/bucket)
#define NBUCK ((NN + 511) / 512)   // 196
#define EPB1 16384                 // edges per partition block
#define NPB1 ((TT + EPB1 - 1) / EPB1)   // 104

typedef _Float16 f16x8 __attribute__((ext_vector_type(8)));
typedef float f32x4 __attribute__((ext_vector_type(4)));

// ---------------- fused preprocessing (cooperative, 196 blocks) ----------------
// phase0: zero gbc, sentinel init, W pre-transpose (fp32 -> fp16 Wt)
// phase1: per-chunk bucket histogram -> gbc        (blocks 0..NPB1-1)
// phase2: exclusive scan of 196 bucket counts      (block 0)
// phase3: partition scatter into dst-buckets       (blocks 0..NPB1-1)
//         record = src | (dst & 511) << 17
// phase4: bucket-local count+scan -> rowptr/dinv, counting sort -> col
//         (block b = bucket b)

__global__ __launch_bounds__(256) void prep_all(
        const int* __restrict__ ei,
        const float* __restrict__ W1, const float* __restrict__ W2,
        const float* __restrict__ W3,
        _Float16* __restrict__ Wt1, _Float16* __restrict__ Wt2,
        _Float16* __restrict__ Wt3,
        int* __restrict__ gbc, int* __restrict__ bbase,
        int* __restrict__ gcursor,
        int* __restrict__ rowptr, float* __restrict__ dinv,
        int* __restrict__ part, int* __restrict__ col) {
    cg::grid_group grid = cg::this_grid();
    __shared__ int hist[NBUCK];
    __shared__ int sA[512];   // scan buf / cnt
    __shared__ int sB[512];   // scn
    __shared__ int sC[512];   // cur
    const int tid = threadIdx.x;
    const int b = blockIdx.x;

    // ---- phase 0 ----
    {
        int idx = b * 256 + tid;
        if (idx < 16384) {
            Wt1[(idx % 128) * 128 + idx / 128] = (_Float16)W1[idx];
        } else if (idx < 32768) {
            int i = idx - 16384;
            Wt2[(i % 128) * 128 + i / 128] = (_Float16)W2[i];
        } else if (idx < 40960) {
            int i = idx - 32768;
            Wt3[(i % 64) * 128 + i / 64] = (_Float16)W3[i];
        }
        if (idx < NBUCK) gbc[idx] = 0;
        if (idx == 0) { bbase[NBUCK] = TT; rowptr[NN] = TT; }
    }
    grid.sync();

    // ---- phase 1: bucket histogram ----
    if (b < NPB1) {
        for (int i = tid; i < NBUCK; i += 256) hist[i] = 0;
        __syncthreads();
        const int base = b * EPB1;
        for (int i = tid; i < EPB1; i += 256) {
            int e = base + i;
            if (e >= TT) break;
            int d = (e < NE) ? ei[NE + e] : (e - NE);
            atomicAdd(&hist[d >> BSH], 1);
        }
        __syncthreads();
        for (int i = tid; i < NBUCK; i += 256)
            if (hist[i]) atomicAdd(&gbc[i], hist[i]);
    }
    grid.sync();

    // ---- phase 2: scan (block 0) ----
    if (b == 0) {
        int v = (tid < NBUCK) ? gbc[tid] : 0;
        sA[tid] = v;
        __syncthreads();
        for (int off = 1; off < 256; off <<= 1) {
            int u = (tid >= off) ? sA[tid - off] : 0;
            __syncthreads();
            sA[tid] += u;
            __syncthreads();
        }
        if (tid < NBUCK) {
            int excl = sA[tid] - v;
            bbase[tid] = excl;
            gcursor[tid] = excl;
        }
    }
    grid.sync();

    // ---- phase 3: partition scatter ----
    if (b < NPB1) {
        for (int i = tid; i < NBUCK; i += 256) hist[i] = 0;
        __syncthreads();
        const int base = b * EPB1;
        for (int i = tid; i < EPB1; i += 256) {
            int e = base + i;
            if (e >= TT) break;
            int d = (e < NE) ? ei[NE + e] : (e - NE);
            atomicAdd(&hist[d >> BSH], 1);
        }
        __syncthreads();
        for (int i = tid; i < NBUCK; i += 256) {
            int cnt = hist[i];
            hist[i] = cnt ? atomicAdd(&gcursor[i], cnt) : 0;
        }
        __syncthreads();
        for (int i = tid; i < EPB1; i += 256) {
            int e = base + i;
            if (e >= TT) break;
            int s, d;
            if (e < NE) { s = ei[e]; d = ei[NE + e]; }
            else        { s = d = e - NE; }
            int pos = atomicAdd(&hist[d >> BSH], 1);
            part[pos] = s | ((d & 511) << 17);
        }
    }
    grid.sync();

    // ---- phase 4: bucket-local rowptr/dinv + counting sort (block b = bucket b)
    {
        const int v0 = b << BSH;
        const int nv = min(512, NN - v0);
        const int base = bbase[b];
        const int nrec = bbase[b + 1] - base;

        sA[tid] = 0; sA[tid + 256] = 0;     // cnt
        __syncthreads();
        for (int i = tid; i < nrec; i += 256)
            atomicAdd(&sA[((unsigned)part[base + i]) >> 17], 1);
        __syncthreads();
        sB[tid] = sA[tid]; sB[tid + 256] = sA[tid + 256];
        __syncthreads();
        for (int off = 1; off < 512; off <<= 1) {
            int a = (tid >= off) ? sB[tid - off] : 0;
            int c = (tid + 256 >= off) ? sB[tid + 256 - off] : 0;
            __syncthreads();
            sB[tid] += a; sB[tid + 256] += c;
            __syncthreads();
        }
#pragma unroll
        for (int p = 0; p < 2; p++) {
            int j = tid + p * 256;
            if (j < nv) {
                int excl = sB[j] - sA[j];
                rowptr[v0 + j] = base + excl;
                dinv[v0 + j] = rsqrtf((float)sA[j]);   // deg >= 1 (self loop)
                sC[j] = base + excl;
            }
        }
        __syncthreads();
        for (int i = tid; i < nrec; i += 256) {
            int r = part[base + i];
            int pos = atomicAdd(&sC[((unsigned)r) >> 17], 1);
            col[pos] = r & 0x1FFFF;
        }
    }
}

// ---------------- MFMA GEMM: Yh[N x F](fp16) = dinv[row] * (A[N x 128] @ W) ----
// Only used for layer 1 (A fp32 = x). Frag layouts m89/m91-verified.

template <int F, bool AHALF>
__global__ __launch_bounds__(256) void gemm_mfma(const void* __restrict__ Ap,
                                                 const _Float16* __restrict__ Wt,
                                                 const float* __restrict__ dinv,
                                                 __half* __restrict__ Yh) {
    constexpr int NT = F / 16;
    __shared__ _Float16 Yl[64][136];

    const int tid = threadIdx.x;
    const int wave = tid >> 6;
    const int lane = tid & 63;
    const int m = lane & 15;
    const int q = lane >> 4;
    const int grow0 = blockIdx.x * 64;
    const int row = grow0 + wave * 16 + m;
    const bool rok = row < NN;

    f32x4 acc[NT];
#pragma unroll
    for (int t = 0; t < NT; t++) acc[t] = (f32x4){0.f, 0.f, 0.f, 0.f};

#pragma unroll
    for (int kt = 0; kt < 128; kt += 32) {
        const int k0 = kt + q * 8;
        union { f16x8 v; _Float16 e[8]; } au;
        if (rok) {
            if constexpr (AHALF) {
                au.v = *reinterpret_cast<const f16x8*>(
                    (const __half*)Ap + (size_t)row * 128 + k0);
            } else {
                const float* A = (const float*)Ap;
                float4 x0 = *reinterpret_cast<const float4*>(A + (size_t)row * 128 + k0);
                float4 x1 = *reinterpret_cast<const float4*>(A + (size_t)row * 128 + k0 + 4);
                au.e[0] = (_Float16)x0.x; au.e[1] = (_Float16)x0.y;
                au.e[2] = (_Float16)x0.z; au.e[3] = (_Float16)x0.w;
                au.e[4] = (_Float16)x1.x; au.e[5] = (_Float16)x1.y;
                au.e[6] = (_Float16)x1.z; au.e[7] = (_Float16)x1.w;
            }
        } else {
#pragma unroll
            for (int j = 0; j < 8; j++) au.e[j] = (_Float16)0.f;
        }
#pragma unroll
        for (int t = 0; t < NT; t++) {
            f16x8 bf = *reinterpret_cast<const f16x8*>(Wt + (t * 16 + m) * 128 + k0);
            acc[t] = __builtin_amdgcn_mfma_f32_16x16x32_f16(au.v, bf, acc[t], 0, 0, 0);
        }
    }
#pragma unroll
    for (int r = 0; r < 4; r++) {
        int lrow = wave * 16 + q * 4 + r;
        int gr = grow0 + lrow;
        float s = (gr < NN) ? dinv[gr] : 0.f;
#pragma unroll
        for (int t = 0; t < NT; t++)
            Yl[lrow][t * 16 + m] = (_Float16)(s * acc[t][r]);
    }
    __syncthreads();
    constexpr int CH = F / 8;
    for (int i = tid; i < 64 * CH; i += 256) {
        int lrow = i / CH, c = i % CH;
        int gr = grow0 + lrow;
        if (gr < NN)
            *reinterpret_cast<f16x8*>(Yh + (size_t)gr * F + c * 8) =
                *reinterpret_cast<const f16x8*>(&Yl[lrow][c * 8]);
    }
}

// ---------------- helper ----------------

__device__ __forceinline__ void acc_add8(float* acc, float4 raw) {
    const __half2* h2 = reinterpret_cast<const __half2*>(&raw);
#pragma unroll
    for (int qq = 0; qq < 4; qq++) {
        float2 fv = __half22float2(h2[qq]);
        acc[2 * qq]     += fv.x;
        acc[2 * qq + 1] += fv.y;
    }
}

// ---------------- fused aggregate + next-layer GEMM (v3, proven) -------------
// Block = 256 thr = 16 nodes. Gather: thread = (node tid/16, f-chunk
// tid%16), serial edge loop unroll 4 -> 4 independent 16B gathers in
// flight per thread. h = relu(dinv[v]*sum + bias) -> LDS. GEMM: 16x128
// @ Wt (16x16x32 MFMA), D scaled by dinv[row] (prescale for the next
// gather), coalesced f16x8 store.

template <int FOUT>
__global__ __launch_bounds__(256) void fused_agg_gemm(
        const __half* __restrict__ XWh,      // [NN][128] fp16, prescaled
        const int* __restrict__ rowptr,
        const int* __restrict__ col,
        const float* __restrict__ dinv,
        const float* __restrict__ bias,      // [128]
        const _Float16* __restrict__ Wt,     // [FOUT][128] fp16
        __half* __restrict__ Yout) {         // [NN][FOUT] fp16, prescaled
    __shared__ _Float16 Hs[16][136];
    __shared__ _Float16 Ds[16][FOUT + 8];

    const int tid = threadIdx.x;
    const int v0 = blockIdx.x * 16;

    // ---- gather phase ----
    {
        const int lnode = tid >> 4;       // 0..15
        const int f = tid & 15;           // 16B chunk
        const int v = v0 + lnode;
        const int beg = rowptr[v];
        const int end = rowptr[v + 1];
        const float4* base = reinterpret_cast<const float4*>(XWh);
        float acc[8] = {0.f, 0.f, 0.f, 0.f, 0.f, 0.f, 0.f, 0.f};
#pragma unroll 4
        for (int e = beg; e < end; e++) {
            int u = col[e];
            float4 raw = base[(size_t)u * 16 + f];
            acc_add8(acc, raw);
        }
        const float dv = dinv[v];
        union { f16x8 v8; _Float16 e8[8]; } hu;
#pragma unroll
        for (int qq = 0; qq < 8; qq++) {
            float r = dv * acc[qq] + bias[f * 8 + qq];
            hu.e8[qq] = (_Float16)fmaxf(r, 0.f);
        }
        *reinterpret_cast<f16x8*>(&Hs[lnode][f * 8]) = hu.v8;
    }
    __syncthreads();

    // ---- GEMM phase: D[16xFOUT] = dinv[row] * (Hs[16x128] @ Wt^T) ----
    constexpr int TPW = FOUT / 64;    // col tiles per wave: 2 (F=128) or 1
    const int wave = tid >> 6;
    const int lane = tid & 63;
    const int m = lane & 15;
    const int q = lane >> 4;
    f32x4 gacc[TPW];
#pragma unroll
    for (int t = 0; t < TPW; t++) gacc[t] = (f32x4){0.f, 0.f, 0.f, 0.f};
#pragma unroll
    for (int kt = 0; kt < 128; kt += 32) {
        const int k0 = kt + q * 8;
        f16x8 av = *reinterpret_cast<const f16x8*>(&Hs[m][k0]);
#pragma unroll
        for (int t = 0; t < TPW; t++) {
            const int gc = (wave * TPW + t) * 16 + m;
            f16x8 bv = *reinterpret_cast<const f16x8*>(Wt + gc * 128 + k0);
            gacc[t] = __builtin_amdgcn_mfma_f32_16x16x32_f16(av, bv, gacc[t], 0, 0, 0);
        }
    }
#pragma unroll
    for (int r = 0; r < 4; r++) {
        const int lrow = q * 4 + r;
        const float s = dinv[v0 + lrow];
#pragma unroll
        for (int t = 0; t < TPW; t++)
            Ds[lrow][(wave * TPW + t) * 16 + m] = (_Float16)(s * gacc[t][r]);
    }
    __syncthreads();
    constexpr int CH = FOUT / 8;
    for (int i2 = tid; i2 < 16 * CH; i2 += 256) {
        int lrow = i2 / CH, c = i2 % CH;
        *reinterpret_cast<f16x8*>(Yout + (size_t)(v0 + lrow) * FOUT + c * 8) =
            *reinterpret_cast<const f16x8*>(&Ds[lrow][c * 8]);
    }
}

// -------- final aggregate: F=64, fp32 out, bias, no relu (round-0 kernel) ----

__global__ __launch_bounds__(256) void agg_final(
        const __half* __restrict__ XWh,      // [NN][64] fp16, prescaled
        const int* __restrict__ rowptr,
        const int* __restrict__ col,
        const float* __restrict__ dinv,
        const float* __restrict__ bias,      // [64]
        float* __restrict__ out) {
    constexpr int TPN = 8;            // 64/8 chunks of 16B
    constexpr int NPB = 256 / TPN;    // 32 nodes/block
    const int v = blockIdx.x * NPB + threadIdx.x / TPN;
    const int f = threadIdx.x % TPN;
    const int beg = rowptr[v];
    const int end = rowptr[v + 1];
    const float4* base = reinterpret_cast<const float4*>(XWh);
    float acc[8] = {0.f, 0.f, 0.f, 0.f, 0.f, 0.f, 0.f, 0.f};
#pragma unroll 4
    for (int e = beg; e < end; e++) {
        int u = col[e];
        float4 raw = base[(size_t)u * TPN + f];
        acc_add8(acc, raw);
    }
    const float dv = dinv[v];
    float r[8];
#pragma unroll
    for (int q = 0; q < 8; q++)
        r[q] = dv * acc[q] + bias[f * 8 + q];
    float* op = out + (size_t)v * 64 + f * 8;
    *reinterpret_cast<float4*>(op)     = make_float4(r[0], r[1], r[2], r[3]);
    *reinterpret_cast<float4*>(op + 4) = make_float4(r[4], r[5], r[6], r[7]);
}

// ---------------- launch ----------------

extern "C" void kernel_launch(void* const* d_in, const int* in_sizes, int n_in,
                              void* d_out, int out_size, void* d_ws, size_t ws_size,
                              hipStream_t stream) {
    const int*   ei = (const int*)d_in[1];
    const float* x  = (const float*)d_in[0];
    const float* W1 = (const float*)d_in[2];
    const float* b1 = (const float*)d_in[3];
    const float* W2 = (const float*)d_in[4];
    const float* b2 = (const float*)d_in[5];
    const float* W3 = (const float*)d_in[6];
    const float* b3 = (const float*)d_in[7];
    float* out = (float*)d_out;

    char* p = (char*)d_ws;
    int*      rowptr  = (int*)p;       p += 400016;
    float*    dinv    = (float*)p;     p += 400000;
    int*      gbc     = (int*)p;       p += 1024;
    int*      bbase   = (int*)p;       p += 1024;
    int*      gcursor = (int*)p;       p += 1024;
    _Float16* Wt1     = (_Float16*)p;  p += 32768;
    _Float16* Wt2     = (_Float16*)p;  p += 32768;
    _Float16* Wt3     = (_Float16*)p;  p += 16384;
    int*      part    = (int*)p;       p += (size_t)TT * 4;       // 6.8 MB
    int*      col     = (int*)p;       p += (size_t)TT * 4;       // 6.8 MB
    __half*   xwh1    = (__half*)p;    p += (size_t)NN * 128 * 2; // 25.6 MB
    __half*   xwh2    = (__half*)p;                                // 25.6 MB
    __half*   xwh3    = xwh1;          // layer-3 input reuses xwh1's space

    // fused preprocessing: one cooperative dispatch replaces
    // memset + wt_conv + bucket_count + scan + p1 + p2
    {
        void* pargs[] = {(void*)&ei, (void*)&W1, (void*)&W2, (void*)&W3,
                         (void*)&Wt1, (void*)&Wt2, (void*)&Wt3,
                         (void*)&gbc, (void*)&bbase, (void*)&gcursor,
                         (void*)&rowptr, (void*)&dinv,
                         (void*)&part, (void*)&col};
        hipLaunchCooperativeKernel((void*)prep_all, dim3(NBUCK), dim3(256),
                                   pargs, 0, stream);
    }

    const int gb = (NN + 63) / 64;   // 1563
    const int fb = NN / 16;          // 6250 (exact)
    // layer 1 GEMM (A fp32): xwh1 = dinv * (x @ W1)
    gemm_mfma<128, false><<<gb, 256, 0, stream>>>(x, Wt1, dinv, xwh1);
    // fused: h1 = relu(dinv*agg(xwh1)+b1); xwh2 = dinv * (h1 @ W2)
    fused_agg_gemm<128><<<fb, 256, 0, stream>>>(xwh1, rowptr, col, dinv, b1,
                                                Wt2, xwh2);
    // fused: h2 = relu(dinv*agg(xwh2)+b2); xwh3 = dinv * (h2 @ W3)
    fused_agg_gemm<64><<<fb, 256, 0, stream>>>(xwh2, rowptr, col, dinv, b2,
                                               Wt3, xwh3);
    // final: out = dinv*agg(xwh3) + b3
    agg_final<<<NN / 32, 256, 0, stream>>>(xwh3, rowptr, col, dinv, b3, out);
}

// Round 6
// 471.427 us; speedup vs baseline: 1.1651x; 1.1651x over previous
//
#include <hip/hip_runtime.h>
#include <hip/hip_fp16.h>

// GCN: 100K nodes, 1.6M edges, 128 -> 128 -> 128 -> 64 (fp32 in/out)
// v7 = v3 hot path (proven best) + prep parallelism fix. v6's coop fusion
// revealed prep = 173us at 8.9% occupancy (latency-bound, NOT launch gaps).
// Fix: EPB 16384->2048 (104->831 blocks for count/p1, ~3.2 blocks/CU),
// scan folded into bucket_count's last block (done-counter), gbc/done
// zeroing folded into wt_conv_all, p2 at 512 threads. 10 -> 8 dispatches.

#define NN 100000
#define NE 1600000
#define TT (NE + NN)              // edges + self loops
#define BSH 9                      // bucket = dst >> 9 (512 nodes/bucket)
#define NBUCK ((NN + 511) / 512)   // 196
#define EPB1 2048                  // edges per partition block
#define NPB1 ((TT + EPB1 - 1) / EPB1)   // 831

typedef _Float16 f16x8 __attribute__((ext_vector_type(8)));
typedef float f32x4 __attribute__((ext_vector_type(4)));

// ------- W pre-transpose + zero gbc/done (runs first, replaces memset) -------

__global__ __launch_bounds__(256) void wt_conv_all(const float* __restrict__ W1,
                                                   const float* __restrict__ W2,
                                                   const float* __restrict__ W3,
                                                   _Float16* __restrict__ Wt1,
                                                   _Float16* __restrict__ Wt2,
                                                   _Float16* __restrict__ Wt3,
                                                   int* __restrict__ gbc,
                                                   int* __restrict__ done,
                                                   int* __restrict__ bbase,
                                                   int* __restrict__ rowptr) {
    int idx = blockIdx.x * 256 + threadIdx.x;
    if (idx < 16384) {
        Wt1[(idx % 128) * 128 + idx / 128] = (_Float16)W1[idx];
    } else if (idx < 32768) {
        int i = idx - 16384;
        Wt2[(i % 128) * 128 + i / 128] = (_Float16)W2[i];
    } else if (idx < 40960) {
        int i = idx - 32768;
        Wt3[(i % 64) * 128 + i / 64] = (_Float16)W3[i];
    }
    if (idx < NBUCK) gbc[idx] = 0;
    if (idx == 0) { *done = 0; bbase[NBUCK] = TT; rowptr[NN] = TT; }
}

// ------- bucket histogram (831 blocks x 2048 edges) + scan in last block -----

__global__ __launch_bounds__(256) void bucket_count(const int* __restrict__ ei,
                                                    int* __restrict__ gbc,
                                                    int* __restrict__ done,
                                                    int* __restrict__ bbase,
                                                    int* __restrict__ gcursor) {
    __shared__ int hist[NBUCK];
    __shared__ int amlast;
    const int tid = threadIdx.x;
    const int base = blockIdx.x * EPB1;
    for (int b = tid; b < NBUCK; b += 256) hist[b] = 0;
    __syncthreads();
    for (int i = tid; i < EPB1; i += 256) {
        int e = base + i;
        if (e >= TT) break;
        int d = (e < NE) ? ei[NE + e] : (e - NE);
        atomicAdd(&hist[d >> BSH], 1);
    }
    __syncthreads();
    for (int b = tid; b < NBUCK; b += 256)
        if (hist[b]) atomicAdd(&gbc[b], hist[b]);
    // last finishing block performs the exclusive scan
    __threadfence();
    if (tid == 0) amlast = (atomicAdd(done, 1) == (int)gridDim.x - 1);
    __syncthreads();
    if (amlast) {
        __threadfence();
        __shared__ int s[256];
        int v = (tid < NBUCK)
            ? __hip_atomic_load(&gbc[tid], __ATOMIC_RELAXED,
                                __HIP_MEMORY_SCOPE_AGENT) : 0;
        s[tid] = v;
        __syncthreads();
        for (int off = 1; off < 256; off <<= 1) {
            int u = (tid >= off) ? s[tid - off] : 0;
            __syncthreads();
            s[tid] += u;
            __syncthreads();
        }
        if (tid < NBUCK) {
            int excl = s[tid] - v;
            bbase[tid] = excl;
            gcursor[tid] = excl;
        }
    }
}

// ---------------- pass 1: partition into 196 dst-buckets ----------------
// record = src | (dst & 511) << 17   (src < 2^17, local dst < 2^9)

__global__ __launch_bounds__(256) void partition_p1(const int* __restrict__ ei,
                                                    int* __restrict__ gcursor,
                                                    int* __restrict__ part) {
    __shared__ int hist[NBUCK];
    const int tid = threadIdx.x;
    const int base = blockIdx.x * EPB1;
    for (int b = tid; b < NBUCK; b += 256) hist[b] = 0;
    __syncthreads();
    for (int i = tid; i < EPB1; i += 256) {
        int e = base + i;
        if (e >= TT) break;
        int d = (e < NE) ? ei[NE + e] : (e - NE);
        atomicAdd(&hist[d >> BSH], 1);
    }
    __syncthreads();
    for (int b = tid; b < NBUCK; b += 256) {
        int cnt = hist[b];
        hist[b] = cnt ? atomicAdd(&gcursor[b], cnt) : 0;
    }
    __syncthreads();
    for (int i = tid; i < EPB1; i += 256) {
        int e = base + i;
        if (e >= TT) break;
        int s, d;
        if (e < NE) { s = ei[e]; d = ei[NE + e]; }
        else        { s = d = e - NE; }
        int pos = atomicAdd(&hist[d >> BSH], 1);
        part[pos] = s | ((d & 511) << 17);
    }
}

// -------- pass 2: bucket-local count + scan + rowptr/dinv + counting sort ----
// 512 threads/block, one block per bucket.

__global__ __launch_bounds__(512) void partition_p2(const int* __restrict__ part,
                                                    const int* __restrict__ bbase,
                                                    int* __restrict__ rowptr,
                                                    float* __restrict__ dinv,
                                                    int* __restrict__ col) {
    __shared__ int cnt[512];
    __shared__ int scn[512];
    __shared__ int cur[512];
    const int b = blockIdx.x;
    const int v0 = b << BSH;
    const int nv = min(512, NN - v0);
    const int tid = threadIdx.x;
    const int base = bbase[b];
    const int nrec = bbase[b + 1] - base;

    cnt[tid] = 0;
    __syncthreads();
    for (int i = tid; i < nrec; i += 512)
        atomicAdd(&cnt[((unsigned)part[base + i]) >> 17], 1);
    __syncthreads();
    scn[tid] = cnt[tid];
    __syncthreads();
    for (int off = 1; off < 512; off <<= 1) {
        int a = (tid >= off) ? scn[tid - off] : 0;
        __syncthreads();
        scn[tid] += a;
        __syncthreads();
    }
    if (tid < nv) {
        int excl = scn[tid] - cnt[tid];
        rowptr[v0 + tid] = base + excl;
        dinv[v0 + tid] = rsqrtf((float)cnt[tid]);   // deg >= 1 (self loop)
        cur[tid] = base + excl;
    }
    __syncthreads();
    for (int i = tid; i < nrec; i += 512) {
        int r = part[base + i];
        int pos = atomicAdd(&cur[((unsigned)r) >> 17], 1);
        col[pos] = r & 0x1FFFF;
    }
}

// ---------------- MFMA GEMM: Yh[N x F](fp16) = dinv[row] * (A[N x 128] @ W) ----
// Only used for layer 1 (A fp32 = x). Frag layouts m89/m91-verified.

template <int F, bool AHALF>
__global__ __launch_bounds__(256) void gemm_mfma(const void* __restrict__ Ap,
                                                 const _Float16* __restrict__ Wt,
                                                 const float* __restrict__ dinv,
                                                 __half* __restrict__ Yh) {
    constexpr int NT = F / 16;
    __shared__ _Float16 Yl[64][136];

    const int tid = threadIdx.x;
    const int wave = tid >> 6;
    const int lane = tid & 63;
    const int m = lane & 15;
    const int q = lane >> 4;
    const int grow0 = blockIdx.x * 64;
    const int row = grow0 + wave * 16 + m;
    const bool rok = row < NN;

    f32x4 acc[NT];
#pragma unroll
    for (int t = 0; t < NT; t++) acc[t] = (f32x4){0.f, 0.f, 0.f, 0.f};

#pragma unroll
    for (int kt = 0; kt < 128; kt += 32) {
        const int k0 = kt + q * 8;
        union { f16x8 v; _Float16 e[8]; } au;
        if (rok) {
            if constexpr (AHALF) {
                au.v = *reinterpret_cast<const f16x8*>(
                    (const __half*)Ap + (size_t)row * 128 + k0);
            } else {
                const float* A = (const float*)Ap;
                float4 x0 = *reinterpret_cast<const float4*>(A + (size_t)row * 128 + k0);
                float4 x1 = *reinterpret_cast<const float4*>(A + (size_t)row * 128 + k0 + 4);
                au.e[0] = (_Float16)x0.x; au.e[1] = (_Float16)x0.y;
                au.e[2] = (_Float16)x0.z; au.e[3] = (_Float16)x0.w;
                au.e[4] = (_Float16)x1.x; au.e[5] = (_Float16)x1.y;
                au.e[6] = (_Float16)x1.z; au.e[7] = (_Float16)x1.w;
            }
        } else {
#pragma unroll
            for (int j = 0; j < 8; j++) au.e[j] = (_Float16)0.f;
        }
#pragma unroll
        for (int t = 0; t < NT; t++) {
            f16x8 bf = *reinterpret_cast<const f16x8*>(Wt + (t * 16 + m) * 128 + k0);
            acc[t] = __builtin_amdgcn_mfma_f32_16x16x32_f16(au.v, bf, acc[t], 0, 0, 0);
        }
    }
#pragma unroll
    for (int r = 0; r < 4; r++) {
        int lrow = wave * 16 + q * 4 + r;
        int gr = grow0 + lrow;
        float s = (gr < NN) ? dinv[gr] : 0.f;
#pragma unroll
        for (int t = 0; t < NT; t++)
            Yl[lrow][t * 16 + m] = (_Float16)(s * acc[t][r]);
    }
    __syncthreads();
    constexpr int CH = F / 8;
    for (int i = tid; i < 64 * CH; i += 256) {
        int lrow = i / CH, c = i % CH;
        int gr = grow0 + lrow;
        if (gr < NN)
            *reinterpret_cast<f16x8*>(Yh + (size_t)gr * F + c * 8) =
                *reinterpret_cast<const f16x8*>(&Yl[lrow][c * 8]);
    }
}

// ---------------- helper ----------------

__device__ __forceinline__ void acc_add8(float* acc, float4 raw) {
    const __half2* h2 = reinterpret_cast<const __half2*>(&raw);
#pragma unroll
    for (int qq = 0; qq < 4; qq++) {
        float2 fv = __half22float2(h2[qq]);
        acc[2 * qq]     += fv.x;
        acc[2 * qq + 1] += fv.y;
    }
}

// ---------------- fused aggregate + next-layer GEMM (v3, proven) -------------
// Block = 256 thr = 16 nodes. Gather: thread = (node tid/16, f-chunk
// tid%16), serial edge loop unroll 4 -> 4 independent 16B gathers in
// flight per thread. h = relu(dinv[v]*sum + bias) -> LDS. GEMM: 16x128
// @ Wt (16x16x32 MFMA), D scaled by dinv[row] (prescale for the next
// gather), coalesced f16x8 store.

template <int FOUT>
__global__ __launch_bounds__(256) void fused_agg_gemm(
        const __half* __restrict__ XWh,      // [NN][128] fp16, prescaled
        const int* __restrict__ rowptr,
        const int* __restrict__ col,
        const float* __restrict__ dinv,
        const float* __restrict__ bias,      // [128]
        const _Float16* __restrict__ Wt,     // [FOUT][128] fp16
        __half* __restrict__ Yout) {         // [NN][FOUT] fp16, prescaled
    __shared__ _Float16 Hs[16][136];
    __shared__ _Float16 Ds[16][FOUT + 8];

    const int tid = threadIdx.x;
    const int v0 = blockIdx.x * 16;

    // ---- gather phase ----
    {
        const int lnode = tid >> 4;       // 0..15
        const int f = tid & 15;           // 16B chunk
        const int v = v0 + lnode;
        const int beg = rowptr[v];
        const int end = rowptr[v + 1];
        const float4* base = reinterpret_cast<const float4*>(XWh);
        float acc[8] = {0.f, 0.f, 0.f, 0.f, 0.f, 0.f, 0.f, 0.f};
#pragma unroll 4
        for (int e = beg; e < end; e++) {
            int u = col[e];
            float4 raw = base[(size_t)u * 16 + f];
            acc_add8(acc, raw);
        }
        const float dv = dinv[v];
        union { f16x8 v8; _Float16 e8[8]; } hu;
#pragma unroll
        for (int qq = 0; qq < 8; qq++) {
            float r = dv * acc[qq] + bias[f * 8 + qq];
            hu.e8[qq] = (_Float16)fmaxf(r, 0.f);
        }
        *reinterpret_cast<f16x8*>(&Hs[lnode][f * 8]) = hu.v8;
    }
    __syncthreads();

    // ---- GEMM phase: D[16xFOUT] = dinv[row] * (Hs[16x128] @ Wt^T) ----
    constexpr int TPW = FOUT / 64;    // col tiles per wave: 2 (F=128) or 1
    const int wave = tid >> 6;
    const int lane = tid & 63;
    const int m = lane & 15;
    const int q = lane >> 4;
    f32x4 gacc[TPW];
#pragma unroll
    for (int t = 0; t < TPW; t++) gacc[t] = (f32x4){0.f, 0.f, 0.f, 0.f};
#pragma unroll
    for (int kt = 0; kt < 128; kt += 32) {
        const int k0 = kt + q * 8;
        f16x8 av = *reinterpret_cast<const f16x8*>(&Hs[m][k0]);
#pragma unroll
        for (int t = 0; t < TPW; t++) {
            const int gc = (wave * TPW + t) * 16 + m;
            f16x8 bv = *reinterpret_cast<const f16x8*>(Wt + gc * 128 + k0);
            gacc[t] = __builtin_amdgcn_mfma_f32_16x16x32_f16(av, bv, gacc[t], 0, 0, 0);
        }
    }
#pragma unroll
    for (int r = 0; r < 4; r++) {
        const int lrow = q * 4 + r;
        const float s = dinv[v0 + lrow];
#pragma unroll
        for (int t = 0; t < TPW; t++)
            Ds[lrow][(wave * TPW + t) * 16 + m] = (_Float16)(s * gacc[t][r]);
    }
    __syncthreads();
    constexpr int CH = FOUT / 8;
    for (int i2 = tid; i2 < 16 * CH; i2 += 256) {
        int lrow = i2 / CH, c = i2 % CH;
        *reinterpret_cast<f16x8*>(Yout + (size_t)(v0 + lrow) * FOUT + c * 8) =
            *reinterpret_cast<const f16x8*>(&Ds[lrow][c * 8]);
    }
}

// -------- final aggregate: F=64, fp32 out, bias, no relu (round-0 kernel) ----

__global__ __launch_bounds__(256) void agg_final(
        const __half* __restrict__ XWh,      // [NN][64] fp16, prescaled
        const int* __restrict__ rowptr,
        const int* __restrict__ col,
        const float* __restrict__ dinv,
        const float* __restrict__ bias,      // [64]
        float* __restrict__ out) {
    constexpr int TPN = 8;            // 64/8 chunks of 16B
    constexpr int NPB = 256 / TPN;    // 32 nodes/block
    const int v = blockIdx.x * NPB + threadIdx.x / TPN;
    const int f = threadIdx.x % TPN;
    const int beg = rowptr[v];
    const int end = rowptr[v + 1];
    const float4* base = reinterpret_cast<const float4*>(XWh);
    float acc[8] = {0.f, 0.f, 0.f, 0.f, 0.f, 0.f, 0.f, 0.f};
#pragma unroll 4
    for (int e = beg; e < end; e++) {
        int u = col[e];
        float4 raw = base[(size_t)u * TPN + f];
        acc_add8(acc, raw);
    }
    const float dv = dinv[v];
    float r[8];
#pragma unroll
    for (int q = 0; q < 8; q++)
        r[q] = dv * acc[q] + bias[f * 8 + q];
    float* op = out + (size_t)v * 64 + f * 8;
    *reinterpret_cast<float4*>(op)     = make_float4(r[0], r[1], r[2], r[3]);
    *reinterpret_cast<float4*>(op + 4) = make_float4(r[4], r[5], r[6], r[7]);
}

// ---------------- launch ----------------

extern "C" void kernel_launch(void* const* d_in, const int* in_sizes, int n_in,
                              void* d_out, int out_size, void* d_ws, size_t ws_size,
                              hipStream_t stream) {
    const float* x  = (const float*)d_in[0];
    const int*   ei = (const int*)d_in[1];
    const float* W1 = (const float*)d_in[2];
    const float* b1 = (const float*)d_in[3];
    const float* W2 = (const float*)d_in[4];
    const float* b2 = (const float*)d_in[5];
    const float* W3 = (const float*)d_in[6];
    const float* b3 = (const float*)d_in[7];
    float* out = (float*)d_out;

    char* p = (char*)d_ws;
    int*      rowptr  = (int*)p;       p += 400016;
    float*    dinv    = (float*)p;     p += 400000;
    int*      gbc     = (int*)p;       p += 1024;
    int*      bbase   = (int*)p;       p += 1024;
    int*      gcursor = (int*)p;       p += 1024;
    int*      done    = (int*)p;       p += 1024;
    _Float16* Wt1     = (_Float16*)p;  p += 32768;
    _Float16* Wt2     = (_Float16*)p;  p += 32768;
    _Float16* Wt3     = (_Float16*)p;  p += 16384;
    int*      part    = (int*)p;       p += (size_t)TT * 4;       // 6.8 MB
    int*      col     = (int*)p;       p += (size_t)TT * 4;       // 6.8 MB
    __half*   xwh1    = (__half*)p;    p += (size_t)NN * 128 * 2; // 25.6 MB
    __half*   xwh2    = (__half*)p;                                // 25.6 MB
    __half*   xwh3    = xwh1;          // layer-3 input reuses xwh1's space

    wt_conv_all<<<160, 256, 0, stream>>>(W1, W2, W3, Wt1, Wt2, Wt3,
                                         gbc, done, bbase, rowptr);
    bucket_count<<<NPB1, 256, 0, stream>>>(ei, gbc, done, bbase, gcursor);
    partition_p1<<<NPB1, 256, 0, stream>>>(ei, gcursor, part);
    partition_p2<<<NBUCK, 512, 0, stream>>>(part, bbase, rowptr, dinv, col);

    const int gb = (NN + 63) / 64;   // 1563
    const int fb = NN / 16;          // 6250 (exact)
    // layer 1 GEMM (A fp32): xwh1 = dinv * (x @ W1)
    gemm_mfma<128, false><<<gb, 256, 0, stream>>>(x, Wt1, dinv, xwh1);
    // fused: h1 = relu(dinv*agg(xwh1)+b1); xwh2 = dinv * (h1 @ W2)
    fused_agg_gemm<128><<<fb, 256, 0, stream>>>(xwh1, rowptr, col, dinv, b1,
                                                Wt2, xwh2);
    // fused: h2 = relu(dinv*agg(xwh2)+b2); xwh3 = dinv * (h2 @ W3)
    fused_agg_gemm<64><<<fb, 256, 0, stream>>>(xwh2, rowptr, col, dinv, b2,
                                               Wt3, xwh3);
    // final: out = dinv*agg(xwh3) + b3
    agg_final<<<NN / 32, 256, 0, stream>>>(xwh3, rowptr, col, dinv, b3, out);
}

// Round 7
// 401.292 us; speedup vs baseline: 1.3687x; 1.1748x over previous
//
#include <hip/hip_runtime.h>
#include <hip/hip_fp16.h>

// GCN: 100K nodes, 1.6M edges, 128 -> 128 -> 128 -> 64 (fp32 in/out)
// v8 = v3 hot path (proven, untouched) + single-pass slack partition.
// Prep history: v3 split prep ~170us (26K threads, latency-bound);
// v6 coop fusion 173us (8.9% occ) -> diagnosed; v7 EPB=2048 regressed
// (163K contended cursor atomics, 40B scatter runs). v8: 208 blocks x
// 1024 threads (EPB 8192, 213K threads), single-pass partition into a
// slack layout part[b*SLOT+pos] (no bucket_count pass), per-block scan
// folded into p2 (196-wide LDS reduction). 10 -> 7 dispatches.

#define NN 100000
#define NE 1600000
#define TT (NE + NN)              // edges + self loops
#define BSH 9                      // bucket = dst >> 9 (512 nodes/bucket)
#define NBUCK ((NN + 511) / 512)   // 196
#define EPB1 8192                  // edges per partition block
#define NPB1 ((TT + EPB1 - 1) / EPB1)   // 208
#define SLOT 12288                 // slack per bucket (exp 8704, ~40 sigma)

typedef _Float16 f16x8 __attribute__((ext_vector_type(8)));
typedef float f32x4 __attribute__((ext_vector_type(4)));

// ------- W pre-transpose + zero gcursor + sentinels (replaces memset) -------

__global__ __launch_bounds__(256) void wt_conv_all(const float* __restrict__ W1,
                                                   const float* __restrict__ W2,
                                                   const float* __restrict__ W3,
                                                   _Float16* __restrict__ Wt1,
                                                   _Float16* __restrict__ Wt2,
                                                   _Float16* __restrict__ Wt3,
                                                   int* __restrict__ gcursor,
                                                   int* __restrict__ rowptr) {
    int idx = blockIdx.x * 256 + threadIdx.x;
    if (idx < 16384) {
        Wt1[(idx % 128) * 128 + idx / 128] = (_Float16)W1[idx];
    } else if (idx < 32768) {
        int i = idx - 16384;
        Wt2[(i % 128) * 128 + i / 128] = (_Float16)W2[i];
    } else if (idx < 40960) {
        int i = idx - 32768;
        Wt3[(i % 64) * 128 + i / 64] = (_Float16)W3[i];
    }
    if (idx < NBUCK) gcursor[idx] = 0;
    if (idx == 0) rowptr[NN] = TT;
}

// ---- single-pass partition: LDS hist -> bucket-space reserve -> scatter ----
// record = src | (dst & 511) << 17   (src < 2^17, local dst < 2^9)
// part is a slack layout: bucket b occupies part[b*SLOT .. b*SLOT+cnt_b).

__global__ __launch_bounds__(1024) void partition_p1(const int* __restrict__ ei,
                                                     int* __restrict__ gcursor,
                                                     int* __restrict__ part) {
    __shared__ int hist[NBUCK];
    const int tid = threadIdx.x;
    const int base = blockIdx.x * EPB1;
    for (int b = tid; b < NBUCK; b += 1024) hist[b] = 0;
    __syncthreads();
    for (int i = tid; i < EPB1; i += 1024) {
        int e = base + i;
        if (e >= TT) break;
        int d = (e < NE) ? ei[NE + e] : (e - NE);
        atomicAdd(&hist[d >> BSH], 1);
    }
    __syncthreads();
    for (int b = tid; b < NBUCK; b += 1024) {
        int cnt = hist[b];
        hist[b] = cnt ? atomicAdd(&gcursor[b], cnt) : 0;   // reserve run
    }
    __syncthreads();
    for (int i = tid; i < EPB1; i += 1024) {
        int e = base + i;
        if (e >= TT) break;
        int s, d;
        if (e < NE) { s = ei[e]; d = ei[NE + e]; }
        else        { s = d = e - NE; }
        int bk = d >> BSH;
        int pos = atomicAdd(&hist[bk], 1);
        part[bk * SLOT + pos] = s | ((d & 511) << 17);
    }
}

// -------- p2: per-block prefix (196-wide reduce) + bucket-local count/scan
// -> rowptr/dinv, counting sort -> col. 512 threads, one block per bucket.

__global__ __launch_bounds__(512) void partition_p2(const int* __restrict__ part,
                                                    const int* __restrict__ gcnt,
                                                    int* __restrict__ rowptr,
                                                    float* __restrict__ dinv,
                                                    int* __restrict__ col) {
    __shared__ int red[512];
    __shared__ int cnt[512];
    __shared__ int scn[512];
    __shared__ int cur[512];
    __shared__ int sbase;
    const int b = blockIdx.x;
    const int v0 = b << BSH;
    const int nv = min(512, NN - v0);
    const int tid = threadIdx.x;
    const int nrec = gcnt[b];
    const int* bp = part + (size_t)b * SLOT;

    // base = sum of counts of buckets < b
    red[tid] = (tid < b) ? gcnt[tid] : 0;
    cnt[tid] = 0;
    __syncthreads();
    for (int off = 256; off > 0; off >>= 1) {
        if (tid < off) red[tid] += red[tid + off];
        __syncthreads();
    }
    if (tid == 0) sbase = red[0];

    for (int i = tid; i < nrec; i += 512)
        atomicAdd(&cnt[((unsigned)bp[i]) >> 17], 1);
    __syncthreads();
    const int base = sbase;
    scn[tid] = cnt[tid];
    __syncthreads();
    for (int off = 1; off < 512; off <<= 1) {
        int a = (tid >= off) ? scn[tid - off] : 0;
        __syncthreads();
        scn[tid] += a;
        __syncthreads();
    }
    if (tid < nv) {
        int excl = scn[tid] - cnt[tid];
        rowptr[v0 + tid] = base + excl;
        dinv[v0 + tid] = rsqrtf((float)cnt[tid]);   // deg >= 1 (self loop)
        cur[tid] = base + excl;
    }
    __syncthreads();
    for (int i = tid; i < nrec; i += 512) {
        int r = bp[i];
        int pos = atomicAdd(&cur[((unsigned)r) >> 17], 1);
        col[pos] = r & 0x1FFFF;
    }
}

// ---------------- MFMA GEMM: Yh[N x F](fp16) = dinv[row] * (A[N x 128] @ W) ----
// Only used for layer 1 (A fp32 = x). Frag layouts m89/m91-verified.

template <int F, bool AHALF>
__global__ __launch_bounds__(256) void gemm_mfma(const void* __restrict__ Ap,
                                                 const _Float16* __restrict__ Wt,
                                                 const float* __restrict__ dinv,
                                                 __half* __restrict__ Yh) {
    constexpr int NT = F / 16;
    __shared__ _Float16 Yl[64][136];

    const int tid = threadIdx.x;
    const int wave = tid >> 6;
    const int lane = tid & 63;
    const int m = lane & 15;
    const int q = lane >> 4;
    const int grow0 = blockIdx.x * 64;
    const int row = grow0 + wave * 16 + m;
    const bool rok = row < NN;

    f32x4 acc[NT];
#pragma unroll
    for (int t = 0; t < NT; t++) acc[t] = (f32x4){0.f, 0.f, 0.f, 0.f};

#pragma unroll
    for (int kt = 0; kt < 128; kt += 32) {
        const int k0 = kt + q * 8;
        union { f16x8 v; _Float16 e[8]; } au;
        if (rok) {
            if constexpr (AHALF) {
                au.v = *reinterpret_cast<const f16x8*>(
                    (const __half*)Ap + (size_t)row * 128 + k0);
            } else {
                const float* A = (const float*)Ap;
                float4 x0 = *reinterpret_cast<const float4*>(A + (size_t)row * 128 + k0);
                float4 x1 = *reinterpret_cast<const float4*>(A + (size_t)row * 128 + k0 + 4);
                au.e[0] = (_Float16)x0.x; au.e[1] = (_Float16)x0.y;
                au.e[2] = (_Float16)x0.z; au.e[3] = (_Float16)x0.w;
                au.e[4] = (_Float16)x1.x; au.e[5] = (_Float16)x1.y;
                au.e[6] = (_Float16)x1.z; au.e[7] = (_Float16)x1.w;
            }
        } else {
#pragma unroll
            for (int j = 0; j < 8; j++) au.e[j] = (_Float16)0.f;
        }
#pragma unroll
        for (int t = 0; t < NT; t++) {
            f16x8 bf = *reinterpret_cast<const f16x8*>(Wt + (t * 16 + m) * 128 + k0);
            acc[t] = __builtin_amdgcn_mfma_f32_16x16x32_f16(au.v, bf, acc[t], 0, 0, 0);
        }
    }
#pragma unroll
    for (int r = 0; r < 4; r++) {
        int lrow = wave * 16 + q * 4 + r;
        int gr = grow0 + lrow;
        float s = (gr < NN) ? dinv[gr] : 0.f;
#pragma unroll
        for (int t = 0; t < NT; t++)
            Yl[lrow][t * 16 + m] = (_Float16)(s * acc[t][r]);
    }
    __syncthreads();
    constexpr int CH = F / 8;
    for (int i = tid; i < 64 * CH; i += 256) {
        int lrow = i / CH, c = i % CH;
        int gr = grow0 + lrow;
        if (gr < NN)
            *reinterpret_cast<f16x8*>(Yh + (size_t)gr * F + c * 8) =
                *reinterpret_cast<const f16x8*>(&Yl[lrow][c * 8]);
    }
}

// ---------------- helper ----------------

__device__ __forceinline__ void acc_add8(float* acc, float4 raw) {
    const __half2* h2 = reinterpret_cast<const __half2*>(&raw);
#pragma unroll
    for (int qq = 0; qq < 4; qq++) {
        float2 fv = __half22float2(h2[qq]);
        acc[2 * qq]     += fv.x;
        acc[2 * qq + 1] += fv.y;
    }
}

// ---------------- fused aggregate + next-layer GEMM (v3, proven) -------------
// Block = 256 thr = 16 nodes. Gather: thread = (node tid/16, f-chunk
// tid%16), serial edge loop unroll 4 -> 4 independent 16B gathers in
// flight per thread. h = relu(dinv[v]*sum + bias) -> LDS. GEMM: 16x128
// @ Wt (16x16x32 MFMA), D scaled by dinv[row] (prescale for the next
// gather), coalesced f16x8 store.

template <int FOUT>
__global__ __launch_bounds__(256) void fused_agg_gemm(
        const __half* __restrict__ XWh,      // [NN][128] fp16, prescaled
        const int* __restrict__ rowptr,
        const int* __restrict__ col,
        const float* __restrict__ dinv,
        const float* __restrict__ bias,      // [128]
        const _Float16* __restrict__ Wt,     // [FOUT][128] fp16
        __half* __restrict__ Yout) {         // [NN][FOUT] fp16, prescaled
    __shared__ _Float16 Hs[16][136];
    __shared__ _Float16 Ds[16][FOUT + 8];

    const int tid = threadIdx.x;
    const int v0 = blockIdx.x * 16;

    // ---- gather phase ----
    {
        const int lnode = tid >> 4;       // 0..15
        const int f = tid & 15;           // 16B chunk
        const int v = v0 + lnode;
        const int beg = rowptr[v];
        const int end = rowptr[v + 1];
        const float4* base = reinterpret_cast<const float4*>(XWh);
        float acc[8] = {0.f, 0.f, 0.f, 0.f, 0.f, 0.f, 0.f, 0.f};
#pragma unroll 4
        for (int e = beg; e < end; e++) {
            int u = col[e];
            float4 raw = base[(size_t)u * 16 + f];
            acc_add8(acc, raw);
        }
        const float dv = dinv[v];
        union { f16x8 v8; _Float16 e8[8]; } hu;
#pragma unroll
        for (int qq = 0; qq < 8; qq++) {
            float r = dv * acc[qq] + bias[f * 8 + qq];
            hu.e8[qq] = (_Float16)fmaxf(r, 0.f);
        }
        *reinterpret_cast<f16x8*>(&Hs[lnode][f * 8]) = hu.v8;
    }
    __syncthreads();

    // ---- GEMM phase: D[16xFOUT] = dinv[row] * (Hs[16x128] @ Wt^T) ----
    constexpr int TPW = FOUT / 64;    // col tiles per wave: 2 (F=128) or 1
    const int wave = tid >> 6;
    const int lane = tid & 63;
    const int m = lane & 15;
    const int q = lane >> 4;
    f32x4 gacc[TPW];
#pragma unroll
    for (int t = 0; t < TPW; t++) gacc[t] = (f32x4){0.f, 0.f, 0.f, 0.f};
#pragma unroll
    for (int kt = 0; kt < 128; kt += 32) {
        const int k0 = kt + q * 8;
        f16x8 av = *reinterpret_cast<const f16x8*>(&Hs[m][k0]);
#pragma unroll
        for (int t = 0; t < TPW; t++) {
            const int gc = (wave * TPW + t) * 16 + m;
            f16x8 bv = *reinterpret_cast<const f16x8*>(Wt + gc * 128 + k0);
            gacc[t] = __builtin_amdgcn_mfma_f32_16x16x32_f16(av, bv, gacc[t], 0, 0, 0);
        }
    }
#pragma unroll
    for (int r = 0; r < 4; r++) {
        const int lrow = q * 4 + r;
        const float s = dinv[v0 + lrow];
#pragma unroll
        for (int t = 0; t < TPW; t++)
            Ds[lrow][(wave * TPW + t) * 16 + m] = (_Float16)(s * gacc[t][r]);
    }
    __syncthreads();
    constexpr int CH = FOUT / 8;
    for (int i2 = tid; i2 < 16 * CH; i2 += 256) {
        int lrow = i2 / CH, c = i2 % CH;
        *reinterpret_cast<f16x8*>(Yout + (size_t)(v0 + lrow) * FOUT + c * 8) =
            *reinterpret_cast<const f16x8*>(&Ds[lrow][c * 8]);
    }
}

// -------- final aggregate: F=64, fp32 out, bias, no relu (round-0 kernel) ----

__global__ __launch_bounds__(256) void agg_final(
        const __half* __restrict__ XWh,      // [NN][64] fp16, prescaled
        const int* __restrict__ rowptr,
        const int* __restrict__ col,
        const float* __restrict__ dinv,
        const float* __restrict__ bias,      // [64]
        float* __restrict__ out) {
    constexpr int TPN = 8;            // 64/8 chunks of 16B
    constexpr int NPB = 256 / TPN;    // 32 nodes/block
    const int v = blockIdx.x * NPB + threadIdx.x / TPN;
    const int f = threadIdx.x % TPN;
    const int beg = rowptr[v];
    const int end = rowptr[v + 1];
    const float4* base = reinterpret_cast<const float4*>(XWh);
    float acc[8] = {0.f, 0.f, 0.f, 0.f, 0.f, 0.f, 0.f, 0.f};
#pragma unroll 4
    for (int e = beg; e < end; e++) {
        int u = col[e];
        float4 raw = base[(size_t)u * TPN + f];
        acc_add8(acc, raw);
    }
    const float dv = dinv[v];
    float r[8];
#pragma unroll
    for (int q = 0; q < 8; q++)
        r[q] = dv * acc[q] + bias[f * 8 + q];
    float* op = out + (size_t)v * 64 + f * 8;
    *reinterpret_cast<float4*>(op)     = make_float4(r[0], r[1], r[2], r[3]);
    *reinterpret_cast<float4*>(op + 4) = make_float4(r[4], r[5], r[6], r[7]);
}

// ---------------- launch ----------------

extern "C" void kernel_launch(void* const* d_in, const int* in_sizes, int n_in,
                              void* d_out, int out_size, void* d_ws, size_t ws_size,
                              hipStream_t stream) {
    const float* x  = (const float*)d_in[0];
    const int*   ei = (const int*)d_in[1];
    const float* W1 = (const float*)d_in[2];
    const float* b1 = (const float*)d_in[3];
    const float* W2 = (const float*)d_in[4];
    const float* b2 = (const float*)d_in[5];
    const float* W3 = (const float*)d_in[6];
    const float* b3 = (const float*)d_in[7];
    float* out = (float*)d_out;

    char* p = (char*)d_ws;
    int*      rowptr  = (int*)p;       p += 400016;
    float*    dinv    = (float*)p;     p += 400000;
    int*      gcursor = (int*)p;       p += 1024;
    _Float16* Wt1     = (_Float16*)p;  p += 32768;
    _Float16* Wt2     = (_Float16*)p;  p += 32768;
    _Float16* Wt3     = (_Float16*)p;  p += 16384;
    int*      part    = (int*)p;       p += (size_t)NBUCK * SLOT * 4; // 9.6 MB
    int*      col     = (int*)p;       p += (size_t)TT * 4;           // 6.8 MB
    __half*   xwh1    = (__half*)p;    p += (size_t)NN * 128 * 2;     // 25.6 MB
    __half*   xwh2    = (__half*)p;                                    // 25.6 MB
    __half*   xwh3    = xwh1;          // layer-3 input reuses xwh1's space

    wt_conv_all<<<160, 256, 0, stream>>>(W1, W2, W3, Wt1, Wt2, Wt3,
                                         gcursor, rowptr);
    partition_p1<<<NPB1, 1024, 0, stream>>>(ei, gcursor, part);
    partition_p2<<<NBUCK, 512, 0, stream>>>(part, gcursor, rowptr, dinv, col);

    const int gb = (NN + 63) / 64;   // 1563
    const int fb = NN / 16;          // 6250 (exact)
    // layer 1 GEMM (A fp32): xwh1 = dinv * (x @ W1)
    gemm_mfma<128, false><<<gb, 256, 0, stream>>>(x, Wt1, dinv, xwh1);
    // fused: h1 = relu(dinv*agg(xwh1)+b1); xwh2 = dinv * (h1 @ W2)
    fused_agg_gemm<128><<<fb, 256, 0, stream>>>(xwh1, rowptr, col, dinv, b1,
                                                Wt2, xwh2);
    // fused: h2 = relu(dinv*agg(xwh2)+b2); xwh3 = dinv * (h2 @ W3)
    fused_agg_gemm<64><<<fb, 256, 0, stream>>>(xwh2, rowptr, col, dinv, b2,
                                               Wt3, xwh3);
    // final: out = dinv*agg(xwh3) + b3
    agg_final<<<NN / 32, 256, 0, stream>>>(xwh3, rowptr, col, dinv, b3, out);
}